// Round 7
// baseline (131.274 us; speedup 1.0000x reference)
//
#include <hip/hip_runtime.h>
#include <hip/hip_fp16.h>

// out[b,o] = sum_i x[b,i] * (W[h,i,o] + 0.1*dW[h*ns+s, i, o])
// IN=10, OUT=8.
// Round 7: keep the fp16 combined table C[g] = fp16(W[g/NS] + 0.1*dW[g])
// (64 MB, L3-resident). Compute kernel: ONE lane per token, C row read as
// 10x dwordx4 (16 B) -> 10 L1/L2 requests per token instead of 20.
// x/idx/out use nontemporal hints so streams don't evict C from L2.

#define IN_DIM 10
#define OUT_DIM 8
#define ROW 80  // IN_DIM*OUT_DIM

typedef float f2v __attribute__((ext_vector_type(2)));
typedef float f4v __attribute__((ext_vector_type(4)));
typedef unsigned int u4v __attribute__((ext_vector_type(4)));

struct alignas(16) H8 { __half2 a, b, c, d; };

// Build C: thread handles 8 consecutive elements of dW/C.
__global__ __launch_bounds__(256) void fd5_build(
    const float* __restrict__ W, const float* __restrict__ dW,
    __half* __restrict__ C, unsigned total8, unsigned per_head /* 80*NS */)
{
    const unsigned t = blockIdx.x * blockDim.x + threadIdx.x;
    if (t >= total8) return;
    const unsigned j = t * 8u;
    const unsigned h = j / per_head;
    const unsigned k = j % 80u;

    const float4* dw4 = reinterpret_cast<const float4*>(dW + j);
    const float4* w4  = reinterpret_cast<const float4*>(W + (size_t)h * ROW + k);
    const float4 a = dw4[0], b = dw4[1];
    const float4 wa = w4[0], wb = w4[1];

    H8 o;
    o.a = __floats2half2_rn(fmaf(0.1f, a.x, wa.x), fmaf(0.1f, a.y, wa.y));
    o.b = __floats2half2_rn(fmaf(0.1f, a.z, wa.z), fmaf(0.1f, a.w, wa.w));
    o.c = __floats2half2_rn(fmaf(0.1f, b.x, wb.x), fmaf(0.1f, b.y, wb.y));
    o.d = __floats2half2_rn(fmaf(0.1f, b.z, wb.z), fmaf(0.1f, b.w, wb.w));
    *reinterpret_cast<H8*>(C + j) = o;
}

__device__ __forceinline__ void fd5_accum(float xi, u4v cc, float* acc)
{
#pragma unroll
    for (int q = 0; q < 4; ++q) {
        unsigned u = cc[q];
        const __half2 hh = *reinterpret_cast<const __half2*>(&u);
        const float2 f = __half22float2(hh);
        acc[2 * q]     = fmaf(xi, f.x, acc[2 * q]);
        acc[2 * q + 1] = fmaf(xi, f.y, acc[2 * q + 1]);
    }
}

// One lane per token. C row: 10x 16B loads (cached). Streams: nontemporal.
__global__ __launch_bounds__(256, 4) void fd5_main(
    const float* __restrict__ x, const __half* __restrict__ C,
    const int* __restrict__ head_ix, const int* __restrict__ split_ix,
    float* __restrict__ out, int B, int NS)
{
    const int t = blockIdx.x * blockDim.x + threadIdx.x;
    if (t >= B) return;

    const int h = __builtin_nontemporal_load(head_ix + t);
    const int s = __builtin_nontemporal_load(split_ix + t);
    const size_t g = (size_t)h * (size_t)NS + (size_t)s;
    const u4v* __restrict__ crow = reinterpret_cast<const u4v*>(C + g * ROW);

    // issue all 10 row loads (independent -> deep MLP)
    const u4v c0 = crow[0], c1 = crow[1], c2 = crow[2], c3 = crow[3], c4 = crow[4];
    const u4v c5 = crow[5], c6 = crow[6], c7 = crow[7], c8 = crow[8], c9 = crow[9];

    const f2v* __restrict__ x2 = reinterpret_cast<const f2v*>(x + (size_t)t * 10);
    const f2v p0 = __builtin_nontemporal_load(x2 + 0);
    const f2v p1 = __builtin_nontemporal_load(x2 + 1);
    const f2v p2 = __builtin_nontemporal_load(x2 + 2);
    const f2v p3 = __builtin_nontemporal_load(x2 + 3);
    const f2v p4 = __builtin_nontemporal_load(x2 + 4);

    float acc[8] = {0.f, 0.f, 0.f, 0.f, 0.f, 0.f, 0.f, 0.f};
    fd5_accum(p0[0], c0, acc);
    fd5_accum(p0[1], c1, acc);
    fd5_accum(p1[0], c2, acc);
    fd5_accum(p1[1], c3, acc);
    fd5_accum(p2[0], c4, acc);
    fd5_accum(p2[1], c5, acc);
    fd5_accum(p3[0], c6, acc);
    fd5_accum(p3[1], c7, acc);
    fd5_accum(p4[0], c8, acc);
    fd5_accum(p4[1], c9, acc);

    f4v o0 = {acc[0], acc[1], acc[2], acc[3]};
    f4v o1 = {acc[4], acc[5], acc[6], acc[7]};
    f4v* __restrict__ op = reinterpret_cast<f4v*>(out + (size_t)t * 8);
    __builtin_nontemporal_store(o0, op);
    __builtin_nontemporal_store(o1, op + 1);
}

// Fallback (fp32 direct) if workspace can't hold C.
__global__ __launch_bounds__(256) void fd5_direct(
    const float* __restrict__ x, const float* __restrict__ W, const float* __restrict__ dW,
    const int* __restrict__ head_ix, const int* __restrict__ split_ix,
    const int* __restrict__ nsp, float* __restrict__ out, int B)
{
    const int gid = blockIdx.x * blockDim.x + threadIdx.x;
    const int t = gid >> 1;
    const int hf = gid & 1;
    if (t >= B) return;
    const int ns = nsp[0];
    const int h = head_ix[t];
    const float* wrow = W + (size_t)h * ROW + (size_t)hf * 4;
    const float* drow = dW + ((size_t)h * ns + split_ix[t]) * ROW + (size_t)hf * 4;
    const float2* x2 = reinterpret_cast<const float2*>(x + (size_t)t * 10);
    const float2 p0 = x2[0], p1 = x2[1], p2 = x2[2], p3 = x2[3], p4 = x2[4];
    const float xv[10] = {p0.x, p0.y, p1.x, p1.y, p2.x, p2.y, p3.x, p3.y, p4.x, p4.y};
    float4 acc = make_float4(0.f, 0.f, 0.f, 0.f);
#pragma unroll
    for (int i = 0; i < 10; ++i) {
        const float4 w4 = *reinterpret_cast<const float4*>(wrow + i * 8);
        const float4 d4 = *reinterpret_cast<const float4*>(drow + i * 8);
        const float xi = xv[i], xs = 0.1f * xi;
        acc.x = fmaf(xi, w4.x, fmaf(xs, d4.x, acc.x));
        acc.y = fmaf(xi, w4.y, fmaf(xs, d4.y, acc.y));
        acc.z = fmaf(xi, w4.z, fmaf(xs, d4.z, acc.z));
        acc.w = fmaf(xi, w4.w, fmaf(xs, d4.w, acc.w));
    }
    *reinterpret_cast<float4*>(out + (size_t)t * 8 + (size_t)hf * 4) = acc;
}

extern "C" void kernel_launch(void* const* d_in, const int* in_sizes, int n_in,
                              void* d_out, int out_size, void* d_ws, size_t ws_size,
                              hipStream_t stream) {
    const float* x        = (const float*)d_in[0];
    const float* W        = (const float*)d_in[1];
    const float* dW       = (const float*)d_in[2];
    const int*   head_ix  = (const int*)d_in[3];
    const int*   split_ix = (const int*)d_in[4];
    const int*   nsp      = (const int*)d_in[5];
    float* out = (float*)d_out;

    const int B  = in_sizes[0] / IN_DIM;        // x  [B, 10]
    const int NH = in_sizes[1] / ROW;           // W  [NH, 10, 8]
    const int NS = in_sizes[2] / in_sizes[1];   // dW [NH*NS, 10, 8]

    const int block = 256;

    const size_t c_elems = (size_t)NH * NS * ROW;            // fp16 elements
    const size_t need    = c_elems * sizeof(__half) + 256;

    if (d_ws == nullptr || ws_size < need) {
        const long long lanes = 2LL * B;
        const int fgrid = (int)((lanes + block - 1) / block);
        fd5_direct<<<fgrid, block, 0, stream>>>(x, W, dW, head_ix, split_ix, nsp, out, B);
        return;
    }

    __half* C = (__half*)(((uintptr_t)d_ws + 255) & ~(uintptr_t)255);

    const unsigned total8   = (unsigned)(c_elems / 8);       // threads in build
    const unsigned per_head = (unsigned)(ROW * NS);
    const int bgrid = (int)((total8 + block - 1) / block);
    const int cgrid = (B + block - 1) / block;

    fd5_build<<<bgrid, block, 0, stream>>>(W, dW, C, total8, per_head);
    fd5_main<<<cgrid, block, 0, stream>>>(x, C, head_ix, split_ix, out, B, NS);
}